// Round 12
// baseline (10347.112 us; speedup 1.0000x reference)
//
#include <hip/hip_runtime.h>
#include <cstddef>

// Decoder: B=64, S=400, T=100, E=512, H=512
// R12 = R10 (best, 4628us) + two non-redundant cuts:
//  (1) k_gates folded into k_mm via last-16-blocks finisher (ticket atomic +
//      device fences): 2 dispatches/step, same traffic as R10's k_gates.
//  (2) k_attn at 512 thr/block (2x waves for latency hiding) + 8B fp8
//      phase-C loads (R11-proven). projkey back to f32-A (absmax 0.031).

#define Bdim 64
#define Sdim 400
#define Tdim 100
#define Edim 512
#define Hdim 512
#define H2   1024
#define H3   1536

typedef __attribute__((ext_vector_type(8))) short          bf16x8;
typedef __attribute__((ext_vector_type(8))) unsigned short u16x8;
typedef __attribute__((ext_vector_type(4))) float          f32x4;

__device__ __forceinline__ float bf2f(unsigned short u) {
    return __uint_as_float(((unsigned int)u) << 16);
}
__device__ __forceinline__ unsigned short f2bf(float f) {
    unsigned int x = __float_as_uint(f);
    x += 0x7fffu + ((x >> 16) & 1u);
    return (unsigned short)(x >> 16);
}
__device__ __forceinline__ float fast_tanh(float x) {
    float e = __expf(2.0f * x);
    return 1.0f - 2.0f / (e + 1.0f);
}
__device__ __forceinline__ float sigm(float x) {
    return 1.0f / (1.0f + __expf(-x));
}

// ---- OCP e4m3fn encode ----
__device__ __forceinline__ unsigned char f2fp8(float f) {
    unsigned u = __float_as_uint(f);
    unsigned s = (u >> 24) & 0x80u;
    float a = fabsf(f);
    if (a >= 448.0f) return (unsigned char)(s | 0x7Eu);
    if (a < 0.0009765625f) return (unsigned char)s;
    int e = (int)((u >> 23) & 0xFF) - 127;
    if (e < -6) {
        int q = (int)lrintf(a * 512.0f);
        return (unsigned char)(s | (unsigned)q);
    }
    unsigned mant = u & 0x7FFFFFu;
    unsigned keep = mant >> 20;
    unsigned rem  = mant & 0xFFFFFu;
    if (rem > 0x80000u || (rem == 0x80000u && (keep & 1u))) keep++;
    if (keep == 8u) { keep = 0u; e++; if (e > 8) return (unsigned char)(s | 0x7Eu); }
    return (unsigned char)(s | ((unsigned)(e + 7) << 3) | keep);
}

#if defined(__has_builtin)
#if __has_builtin(__builtin_amdgcn_cvt_pk_f32_fp8)
#define HWFP8 1
#endif
#endif
__device__ __forceinline__ float fp8sw(unsigned char v) {
    unsigned e = (v >> 3) & 15u, m = v & 7u, s = v >> 7;
    float f = e ? __uint_as_float(((e + 120u) << 23) | (m << 20))
                : (float)m * 0.001953125f;
    return s ? -f : f;
}
__device__ __forceinline__ void dec4(unsigned int w, float* o) {
#ifdef HWFP8
    auto lo = __builtin_amdgcn_cvt_pk_f32_fp8(w, false);
    auto hi = __builtin_amdgcn_cvt_pk_f32_fp8(w, true);
    o[0] = lo[0]; o[1] = lo[1]; o[2] = hi[0]; o[3] = hi[1];
#else
    o[0] = fp8sw(w & 0xFF); o[1] = fp8sw((w >> 8) & 0xFF);
    o[2] = fp8sw((w >> 16) & 0xFF); o[3] = fp8sw(w >> 24);
#endif
}

// ---------------- one-time kernels ----------------

__global__ void k_cvt(const float4* __restrict__ in, ushort4* __restrict__ out, int n4) {
    int i = blockIdx.x * blockDim.x + threadIdx.x;
    int stride = gridDim.x * blockDim.x;
    for (; i < n4; i += stride) {
        float4 v = in[i];
        ushort4 u;
        u.x = f2bf(v.x); u.y = f2bf(v.y); u.z = f2bf(v.z); u.w = f2bf(v.w);
        out[i] = u;
    }
}

__global__ void k_cvt8(const float4* __restrict__ in, uchar4* __restrict__ out, int n4) {
    int i = blockIdx.x * blockDim.x + threadIdx.x;
    int stride = gridDim.x * blockDim.x;
    for (; i < n4; i += stride) {
        float4 v = in[i];
        uchar4 u;
        u.x = f2fp8(v.x); u.y = f2fp8(v.y); u.z = f2fp8(v.z); u.w = f2fp8(v.w);
        out[i] = u;
    }
}

__global__ void k_cvtW(
    const float4* __restrict__ Wk, const float4* __restrict__ Wih,
    const float4* __restrict__ Whh, const float4* __restrict__ Wp,
    ushort4* __restrict__ oWk, ushort4* __restrict__ oWih,
    ushort4* __restrict__ oWhh, ushort4* __restrict__ oWp)
{
    int i = blockIdx.x * blockDim.x + threadIdx.x;
    int stride = gridDim.x * blockDim.x;
    for (; i < 1179648; i += stride) {
        const float4* src; ushort4* dst; int k = i;
        if (k < 131072)                     { src = Wk;  dst = oWk;  }
        else if ((k -= 131072) < 589824)    { src = Wih; dst = oWih; }
        else if ((k -= 589824) < 196608)    { src = Whh; dst = oWhh; }
        else { k -= 196608;                   src = Wp;  dst = oWp;  }
        float4 v = src[k];
        ushort4 u;
        u.x = f2bf(v.x); u.y = f2bf(v.y); u.z = f2bf(v.z); u.w = f2bf(v.w);
        dst[k] = u;
    }
}

// pack Wq into k4-major fp8: Wq8p[(k4*512 + j)] = fp8x4(Wq[j][4*k4..])
__global__ __launch_bounds__(256) void k_packWq(
    const float* __restrict__ Wq, uchar4* __restrict__ Wq8p)
{
    int i = blockIdx.x * 256 + threadIdx.x;
    if (i >= 65536) return;
    int k4 = i >> 9, j = i & 511;
    const float* src = Wq + (size_t)j * 512 + (k4 << 2);
    uchar4 u;
    u.x = f2fp8(src[0]); u.y = f2fp8(src[1]);
    u.z = f2fp8(src[2]); u.w = f2fp8(src[3]);
    Wq8p[i] = u;
}

__global__ void k_zero(float* __restrict__ p, int n) {
    int i = blockIdx.x * blockDim.x + threadIdx.x;
    if (i < n) p[i] = 0.0f;
}

__global__ __launch_bounds__(256) void k_init(
    const float* __restrict__ ef, const float* __restrict__ Wi,
    const float* __restrict__ bi, float* __restrict__ h0,
    unsigned short* __restrict__ hb16)
{
    __shared__ float efs[1024];
    int b = blockIdx.x, tid = threadIdx.x;
    for (int i = tid; i < 1024; i += 256) efs[i] = ef[(size_t)b * 1024 + i];
    __syncthreads();
    for (int j = tid; j < 512; j += 256) {
        const float4* w4 = (const float4*)(Wi + (size_t)j * 1024);
        float acc = 0.0f;
        for (int k4 = 0; k4 < 256; k4++) {
            float4 wv = w4[k4];
            int k = k4 << 2;
            acc = fmaf(efs[k],   wv.x, acc);
            acc = fmaf(efs[k+1], wv.y, acc);
            acc = fmaf(efs[k+2], wv.z, acc);
            acc = fmaf(efs[k+3], wv.w, acc);
        }
        float h = fast_tanh(acc + bi[j]);
        h0[(size_t)b * 512 + j] = h;
        hb16[(size_t)b * 512 + j] = f2bf(h);
    }
}

__global__ __launch_bounds__(512) void k_q0(
    const float* __restrict__ h, const float* __restrict__ Wq,
    float* __restrict__ qbuf)
{
    __shared__ float hs[512];
    int b = blockIdx.x, j = threadIdx.x;
    hs[j] = h[(size_t)b * 512 + j];
    __syncthreads();
    const float4* w4 = (const float4*)(Wq + (size_t)j * 512);
    float acc = 0.0f;
    #pragma unroll 4
    for (int k4 = 0; k4 < 128; k4++) {
        float4 wv = w4[k4];
        int k = k4 << 2;
        acc = fmaf(hs[k],   wv.x, acc);
        acc = fmaf(hs[k+1], wv.y, acc);
        acc = fmaf(hs[k+2], wv.z, acc);
        acc = fmaf(hs[k+3], wv.w, acc);
    }
    qbuf[(size_t)b * 512 + j] = acc;
}

// MFMA bf16 GEMM: C[M][N] = A[M][K] @ B[N][K]^T. (verified R2/R4/R7-R11)
__global__ __launch_bounds__(256) void k_mfma_gemm(
    const float* __restrict__ Af,
    const unsigned short* __restrict__ A0, const unsigned short* __restrict__ A1,
    const unsigned short* __restrict__ A2,
    int ld0, int ld1, int ld2, int s1, int s2,
    const unsigned short* __restrict__ Bw, int ldb,
    float* __restrict__ Cf, unsigned short* __restrict__ Cb,
    unsigned char* __restrict__ C8, int ldc,
    const float* __restrict__ bias, int K)
{
    __shared__ __attribute__((aligned(16))) unsigned short As[128][40];
    __shared__ __attribute__((aligned(16))) unsigned short Bs[128][40];
    int m0 = blockIdx.x << 7, n0 = blockIdx.y << 7;
    int tid = threadIdx.x;
    int wave = tid >> 6, lane = tid & 63;
    int wr = (wave >> 1) << 6, wc = (wave & 1) << 6;
    int fr = lane & 15, fq = lane >> 4;
    f32x4 acc[4][4];
    #pragma unroll
    for (int i = 0; i < 4; i++)
        #pragma unroll
        for (int j = 0; j < 4; j++)
            acc[i][j] = (f32x4){0.f, 0.f, 0.f, 0.f};
    int lrow = tid >> 1;
    int lk = (tid & 1) << 4;
    for (int k0 = 0; k0 < K; k0 += 32) {
        u16x8 av0, av1;
        if (Af) {
            const float* ap = Af + (size_t)(m0 + lrow) * ld0 + k0 + lk;
            float4 f0 = *(const float4*)ap;
            float4 f1 = *(const float4*)(ap + 4);
            float4 f2 = *(const float4*)(ap + 8);
            float4 f3 = *(const float4*)(ap + 12);
            av0[0]=f2bf(f0.x); av0[1]=f2bf(f0.y); av0[2]=f2bf(f0.z); av0[3]=f2bf(f0.w);
            av0[4]=f2bf(f1.x); av0[5]=f2bf(f1.y); av0[6]=f2bf(f1.z); av0[7]=f2bf(f1.w);
            av1[0]=f2bf(f2.x); av1[1]=f2bf(f2.y); av1[2]=f2bf(f2.z); av1[3]=f2bf(f2.w);
            av1[4]=f2bf(f3.x); av1[5]=f2bf(f3.y); av1[6]=f2bf(f3.z); av1[7]=f2bf(f3.w);
        } else {
            const unsigned short* Ap; int lda_, ka;
            if (k0 < s1)      { Ap = A0; lda_ = ld0; ka = k0; }
            else if (k0 < s2) { Ap = A1; lda_ = ld1; ka = k0 - s1; }
            else              { Ap = A2; lda_ = ld2; ka = k0 - s2; }
            const unsigned short* ap = Ap + (size_t)(m0 + lrow) * lda_ + ka + lk;
            av0 = *(const u16x8*)ap;
            av1 = *(const u16x8*)(ap + 8);
        }
        const unsigned short* bp_ = Bw + (size_t)(n0 + lrow) * ldb + k0 + lk;
        u16x8 bv0 = *(const u16x8*)bp_;
        u16x8 bv1 = *(const u16x8*)(bp_ + 8);
        __syncthreads();
        *(u16x8*)&As[lrow][lk] = av0;
        *(u16x8*)&As[lrow][lk + 8] = av1;
        *(u16x8*)&Bs[lrow][lk] = bv0;
        *(u16x8*)&Bs[lrow][lk + 8] = bv1;
        __syncthreads();
        bf16x8 af[4], bf[4];
        #pragma unroll
        for (int i = 0; i < 4; i++) {
            af[i] = *(const bf16x8*)&As[wr + (i << 4) + fr][fq << 3];
            bf[i] = *(const bf16x8*)&Bs[wc + (i << 4) + fr][fq << 3];
        }
        #pragma unroll
        for (int i = 0; i < 4; i++)
            #pragma unroll
            for (int j = 0; j < 4; j++)
                acc[i][j] = __builtin_amdgcn_mfma_f32_16x16x32_bf16(af[i], bf[j], acc[i][j], 0, 0, 0);
    }
    #pragma unroll
    for (int j = 0; j < 4; j++) {
        int col = n0 + wc + (j << 4) + fr;
        float bv = bias ? bias[col] : 0.0f;
        #pragma unroll
        for (int i = 0; i < 4; i++) {
            int rbase = m0 + wr + (i << 4) + (fq << 2);
            #pragma unroll
            for (int r = 0; r < 4; r++) {
                float v = acc[i][j][r] + bv;
                if (C8)      C8[(size_t)(rbase + r) * ldc + col] = f2fp8(v);
                else if (Cb) Cb[(size_t)(rbase + r) * ldc + col] = f2bf(v);
                else         Cf[(size_t)(rbase + r) * ldc + col] = v;
            }
        }
    }
}

// ---------------- per-step kernel 1: attention (512 thr) ----------------
// 512 blocks (b = bid>>3, c = bid&7; 8 s-chunks of 50), 512 threads (8 waves).
// No-max exp (R4/R10-proven), atomic ctx into complete ctxf[t&1].
__global__ __launch_bounds__(512) void k_attn(
    const unsigned char* __restrict__ pkb8, const unsigned char* __restrict__ ehb8,
    const float* __restrict__ qbuf, const float* __restrict__ We,
    float* __restrict__ ctxf, float* __restrict__ sumcA, int t)
{
    int bid = blockIdx.x;
    int b = bid >> 3, c = bid & 7;
    int s0 = c * 50;
    int tid = threadIdx.x, wave = tid >> 6, lane = tid & 63;
    int s = t & 1;
    __shared__ float qS[512];
    __shared__ float eL[52], pL[52];
    __shared__ float cbuf[3072];

    // zero the other ping-pong slot for next step
    {
        int gid = bid * 512 + tid;
        float* octx = ctxf + ((size_t)(1 - s) << 16);
        if (gid < 65536) octx[gid] = 0.0f;
        if (gid < 64) sumcA[(1 - s) * 64 + gid] = 0.0f;
    }
    qS[tid] = qbuf[(size_t)b * 512 + tid];
    __syncthreads();

    float q8[8], w8[8];
    {
        #pragma unroll
        for (int jj = 0; jj < 8; jj++) q8[jj] = qS[(lane << 3) + jj];
        const float4* wp = (const float4*)(We + (lane << 3));
        float4 w0 = wp[0], w1 = wp[1];
        w8[0]=w0.x; w8[1]=w0.y; w8[2]=w0.z; w8[3]=w0.w;
        w8[4]=w1.x; w8[5]=w1.y; w8[6]=w1.z; w8[7]=w1.w;
    }
    // phase A: energies, one wave per s row (8 waves -> 6-7 rows each)
    for (int sl = wave; sl < 50; sl += 8) {
        const unsigned char* pr = pkb8 + ((size_t)(b * Sdim + s0 + sl) << 9) + (lane << 3);
        uint2 u = *(const uint2*)pr;
        float p[8];
        dec4(u.x, p); dec4(u.y, p + 4);
        float sum = 0.0f;
        #pragma unroll
        for (int jj = 0; jj < 8; jj++)
            sum = fmaf(fast_tanh(q8[jj] + p[jj]), w8[jj], sum);
        #pragma unroll
        for (int off = 32; off > 0; off >>= 1) sum += __shfl_xor(sum, off, 64);
        if (lane == 0) eL[sl] = sum;
    }
    __syncthreads();
    // phase B: p = exp(e) (no max), chunk sum -> atomic global sum
    if (wave == 0) {
        float pv = 0.0f;
        if (lane < 50) { pv = __expf(eL[lane]); pL[lane] = pv; }
        float ssum = pv;
        #pragma unroll
        for (int off = 32; off > 0; off >>= 1) ssum += __shfl_xor(ssum, off, 64);
        if (lane == 0) atomicAdd(&sumcA[s * 64 + b], ssum);
    }
    __syncthreads();
    // phase C: exp-weighted ctx partial, 8B fp8 loads, 4 row-groups
    int g = tid >> 7, d0 = (tid & 127) << 3;
    float a[8] = {};
    const unsigned char* eb = ehb8 + ((size_t)(b * Sdim + s0) << 10) + d0;
    for (int sl = g; sl < 50; sl += 4) {
        float pp = pL[sl];
        uint2 u = *(const uint2*)(eb + ((size_t)sl << 10));
        float v[8];
        dec4(u.x, v); dec4(u.y, v + 4);
        #pragma unroll
        for (int jj = 0; jj < 8; jj++) a[jj] = fmaf(pp, v[jj], a[jj]);
    }
    if (g) {
        #pragma unroll
        for (int jj = 0; jj < 8; jj++) cbuf[(g - 1) * 1024 + d0 + jj] = a[jj];
    }
    __syncthreads();
    if (!g) {
        float* cp = ctxf + ((size_t)s << 16) + ((size_t)b << 10) + d0;
        #pragma unroll
        for (int jj = 0; jj < 8; jj++)
            atomicAdd(cp + jj, a[jj] + cbuf[d0 + jj] + cbuf[1024 + d0 + jj] + cbuf[2048 + d0 + jj]);
    }
}

// ---------------- per-step kernel 2: K-split GRU GEMMs + finisher gates ----
// 144 blocks x 512 thr: 0..95 gi-ctx (4 K-chunks x 24 N), 96..143 gh (2 x 24).
// After partial writes: __threadfence + ticket. Last 16 blocks spin for all
// 144, re-fence, then compute gates+h+q for 4 batches each (= R10 k_gates).
__global__ __launch_bounds__(512) void k_mm(
    const float* __restrict__ ctxf, const float* __restrict__ sumcA,
    const unsigned short* __restrict__ hb16,
    const unsigned short* __restrict__ Wihb, const unsigned short* __restrict__ Whhb,
    float* __restrict__ pgi, float* __restrict__ pgh,
    unsigned short* __restrict__ csb,
    const unsigned short* __restrict__ giEb,
    const float* __restrict__ bih, const float* __restrict__ bhh,
    const float* __restrict__ hcur, float* __restrict__ hnext,
    const unsigned char* __restrict__ Wq8p, float* __restrict__ qbuf,
    float* __restrict__ ds, unsigned short* __restrict__ dsb,
    unsigned short* __restrict__ hb16w, float* __restrict__ hlast,
    int* __restrict__ ctr, int t)
{
    __shared__ __attribute__((aligned(16))) unsigned short As[64][264];
    __shared__ __attribute__((aligned(16))) unsigned short Ws[64][72];
    __shared__ int rankS;
    int bid = blockIdx.x, tid = threadIdx.x;
    int wave = tid >> 6, lane = tid & 63;
    int s = t & 1;
    bool isGi = bid < 96;
    int kc, nb;
    if (isGi) { kc = bid / 24; nb = bid - kc * 24; }
    else      { int x = bid - 96; kc = x / 24; nb = x - kc * 24; }
    int n0 = nb << 6;

    int r = tid >> 3, c0 = (tid & 7) << 5;
    if (isGi) {
        float inv = 1.0f / sumcA[s * 64 + r];
        const float* pc = ctxf + ((size_t)s << 16) + ((size_t)r << 10) + (kc << 8) + c0;
        #pragma unroll
        for (int k4 = 0; k4 < 8; k4++) {
            float4 v = *(const float4*)(pc + (k4 << 2));
            ushort4 u;
            u.x = f2bf(v.x * inv); u.y = f2bf(v.y * inv);
            u.z = f2bf(v.z * inv); u.w = f2bf(v.w * inv);
            *(ushort4*)&As[r][c0 + (k4 << 2)] = u;
            if (nb == 0)
                *(ushort4*)&csb[(((size_t)(r * Tdim + t)) << 10) + (kc << 8) + c0 + (k4 << 2)] = u;
        }
    } else {
        const unsigned short* ph = hb16 + (size_t)r * 512 + (kc << 8) + c0;
        *(u16x8*)&As[r][c0]      = *(const u16x8*)ph;
        *(u16x8*)&As[r][c0 + 8]  = *(const u16x8*)(ph + 8);
        *(u16x8*)&As[r][c0 + 16] = *(const u16x8*)(ph + 16);
        *(u16x8*)&As[r][c0 + 24] = *(const u16x8*)(ph + 24);
    }
    __syncthreads();

    const unsigned short* Wsrc = isGi ? (Wihb + (size_t)n0 * H3 + 512 + (kc << 8))
                                      : (Whhb + (size_t)n0 * Hdim + (kc << 8));
    int ldw = isGi ? H3 : Hdim;
    int fr = lane & 15, fq = lane >> 4;
    int fi = wave >> 1, fj0 = (wave & 1) << 1;
    f32x4 acc0 = {0.f,0.f,0.f,0.f}, acc1 = {0.f,0.f,0.f,0.f};
    int rw = tid >> 3, cw2 = (tid & 7) << 3;
    for (int ch = 0; ch < 4; ch++) {
        __syncthreads();
        u16x8 wv8 = *(const u16x8*)(Wsrc + (size_t)rw * ldw + (ch << 6) + cw2);
        *(u16x8*)&Ws[rw][cw2] = wv8;
        __syncthreads();
        #pragma unroll
        for (int ss = 0; ss < 2; ss++) {
            bf16x8 af = *(const bf16x8*)&As[(fi << 4) + fr][(ch << 6) + (ss << 5) + (fq << 3)];
            bf16x8 b0 = *(const bf16x8*)&Ws[(fj0 << 4) + fr][(ss << 5) + (fq << 3)];
            bf16x8 b1 = *(const bf16x8*)&Ws[((fj0 + 1) << 4) + fr][(ss << 5) + (fq << 3)];
            acc0 = __builtin_amdgcn_mfma_f32_16x16x32_bf16(af, b0, acc0, 0, 0, 0);
            acc1 = __builtin_amdgcn_mfma_f32_16x16x32_bf16(af, b1, acc1, 0, 0, 0);
        }
    }
    float* outp = (isGi ? pgi : pgh) + (size_t)kc * Bdim * H3;
    int rowb = (fi << 4) + (fq << 2);
    #pragma unroll
    for (int r4 = 0; r4 < 4; r4++) {
        outp[(size_t)(rowb + r4) * H3 + n0 + (fj0 << 4) + fr] = acc0[r4];
        outp[(size_t)(rowb + r4) * H3 + n0 + ((fj0 + 1) << 4) + fr] = acc1[r4];
    }

    // ---- ticket + finisher (last 16 blocks do gates for 4 batches each) ----
    __threadfence();
    __syncthreads();
    if (tid == 0) rankS = atomicAdd(&ctr[t], 1);
    __syncthreads();
    int rank = rankS;
    if (rank < 128) return;
    if (tid == 0) { while (atomicAdd(&ctr[t], 0) < 144) { } }
    __syncthreads();
    __threadfence();

    int b0 = (rank - 128) << 2;
    float* hnS = (float*)&As[0][0];   // reuse LDS: 4 x 512 f32 = 8KB
    int jj = tid;                      // 512 threads = one j each
    #pragma unroll
    for (int bb = 0; bb < 4; bb++) {
        int b = b0 + bb;
        size_t m = (size_t)b * Tdim + t;
        float gi0 = 0, gi1 = 0, gi2 = 0, gh0 = 0, gh1 = 0, gh2 = 0;
        #pragma unroll
        for (int cc = 0; cc < 4; cc++) {
            const float* p = pgi + ((size_t)(cc * 64 + b)) * H3;
            gi0 += p[jj]; gi1 += p[jj + 512]; gi2 += p[jj + 1024];
        }
        #pragma unroll
        for (int cc = 0; cc < 2; cc++) {
            const float* p = pgh + ((size_t)(cc * 64 + b)) * H3;
            gh0 += p[jj]; gh1 += p[jj + 512]; gh2 += p[jj + 1024];
        }
        const unsigned short* ge = giEb + m * H3;
        gi0 += bf2f(ge[jj])        + bih[jj];
        gi1 += bf2f(ge[jj + 512])  + bih[jj + 512];
        gi2 += bf2f(ge[jj + 1024]) + bih[jj + 1024];
        gh0 += bhh[jj]; gh1 += bhh[jj + 512]; gh2 += bhh[jj + 1024];
        float rg = sigm(gi0 + gh0);
        float zz = sigm(gi1 + gh1);
        float nn = fast_tanh(gi2 + rg * gh2);
        float hp = hcur[(size_t)b * 512 + jj];
        float hn = (1.0f - zz) * nn + zz * hp;
        ds[m * 512 + jj] = hn;
        dsb[m * 512 + jj] = f2bf(hn);
        hb16w[(size_t)b * 512 + jj] = f2bf(hn);
        hnext[(size_t)b * 512 + jj] = hn;
        hlast[(size_t)b * 512 + jj] = hn;   // final overwrite = h_last
        hnS[bb * 512 + jj] = hn;
    }
    __syncthreads();
    // q_{t+1}[b0..b0+4][jj] via fp8 packed Wq (k4-major, coalesced)
    float qa[4] = {0.f, 0.f, 0.f, 0.f};
    const unsigned int* wp = (const unsigned int*)Wq8p + jj;
    #pragma unroll 2
    for (int k4 = 0; k4 < 128; k4++) {
        unsigned int wv = wp[(size_t)k4 << 9];
        float d[4];
        dec4(wv, d);
        #pragma unroll
        for (int bb = 0; bb < 4; bb++) {
            const float* hv = &hnS[bb * 512 + (k4 << 2)];
            qa[bb] = fmaf(hv[0], d[0], qa[bb]);
            qa[bb] = fmaf(hv[1], d[1], qa[bb]);
            qa[bb] = fmaf(hv[2], d[2], qa[bb]);
            qa[bb] = fmaf(hv[3], d[3], qa[bb]);
        }
    }
    #pragma unroll
    for (int bb = 0; bb < 4; bb++)
        qbuf[(size_t)(b0 + bb) * 512 + jj] = qa[bb];
}

extern "C" void kernel_launch(void* const* d_in, const int* in_sizes, int n_in,
                              void* d_out, int out_size, void* d_ws, size_t ws_size,
                              hipStream_t stream) {
    const float* te  = (const float*)d_in[0];
    const float* eh  = (const float*)d_in[1];
    const float* ef  = (const float*)d_in[2];
    const float* Wi  = (const float*)d_in[3];
    const float* bi  = (const float*)d_in[4];
    const float* Wk  = (const float*)d_in[5];
    const float* Wq  = (const float*)d_in[6];
    const float* We  = (const float*)d_in[7];
    const float* Wih = (const float*)d_in[8];
    const float* Whh = (const float*)d_in[9];
    const float* bih = (const float*)d_in[10];
    const float* bhh = (const float*)d_in[11];
    const float* Wp  = (const float*)d_in[12];
    const float* bp  = (const float*)d_in[13];

    float* out     = (float*)d_out;
    float* out_ds  = out;
    float* out_hl  = out + (size_t)Bdim * Tdim * Hdim;
    float* out_pre = out_hl + (size_t)Bdim * Hdim;

    // ---- workspace ----
    char* w = (char*)d_ws;
    size_t o = 0;
    unsigned char*  pkb8 = (unsigned char*)(w + o);  o += (size_t)25600 * 512;
    unsigned char*  ehb8 = (unsigned char*)(w + o);  o += (size_t)25600 * 1024;
    unsigned short* teb  = (unsigned short*)(w + o); o += (size_t)6400 * 512 * 2;
    unsigned short* Wkb  = (unsigned short*)(w + o); o += (size_t)512 * 1024 * 2;
    unsigned short* Wihb = (unsigned short*)(w + o); o += (size_t)1536 * 1536 * 2;
    unsigned short* Whhb = (unsigned short*)(w + o); o += (size_t)1536 * 512 * 2;
    unsigned short* Wpb  = (unsigned short*)(w + o); o += (size_t)512 * 2048 * 2;
    unsigned char*  Wq8p = (unsigned char*)(w + o);  o += (size_t)512 * 512;
    unsigned short* dsb  = (unsigned short*)(w + o); o += (size_t)6400 * 512 * 2;
    unsigned short* csb  = (unsigned short*)(w + o); o += (size_t)6400 * 1024 * 2;
    unsigned short* giEb = (unsigned short*)(w + o); o += (size_t)6400 * 1536 * 2;
    unsigned short* hb16 = (unsigned short*)(w + o); o += (size_t)Bdim * 512 * 2;
    float* qbuf  = (float*)(w + o); o += (size_t)Bdim * 512 * 4;
    float* hbuf  = (float*)(w + o); o += (size_t)2 * Bdim * 512 * 4;   // ping-pong
    float* ctxf  = (float*)(w + o); o += (size_t)2 * Bdim * 1024 * 4;  // ping-pong
    float* sumcA = (float*)(w + o); o += 128 * 4;
    int*   ctr   = (int*)(w + o);   o += 128 * 4;                      // per-t tickets
    float* pgi   = (float*)(w + o); o += (size_t)4 * Bdim * H3 * 4;
    float* pgh   = (float*)(w + o); o += (size_t)2 * Bdim * H3 * 4;

    // ---- one-time prep ----
    k_cvt8<<<2048, 256, 0, stream>>>((const float4*)eh, (uchar4*)ehb8, 6553600);
    k_cvt<<<512, 256, 0, stream>>>((const float4*)te, (ushort4*)teb, 819200);
    k_cvtW<<<1024, 256, 0, stream>>>(
        (const float4*)Wk, (const float4*)Wih, (const float4*)Whh, (const float4*)Wp,
        (ushort4*)Wkb, (ushort4*)Wihb, (ushort4*)Whhb, (ushort4*)Wpb);
    k_packWq<<<256, 256, 0, stream>>>(Wq, (uchar4*)Wq8p);
    k_zero<<<515, 256, 0, stream>>>(ctxf, 2 * 65536 + 256);   // ctxf+sumcA+ctr contiguous
    k_init<<<Bdim, 256, 0, stream>>>(ef, Wi, bi, hbuf, hb16);
    k_q0<<<Bdim, 512, 0, stream>>>(hbuf, Wq, qbuf);
    // proj_key = eh(f32) @ Wkb^T -> pkb8 (fp8), M=25600 N=512 K=1024
    k_mfma_gemm<<<dim3(200, 4), 256, 0, stream>>>(
        eh, nullptr, nullptr, nullptr, 1024, 0, 0, 1024, 1024,
        Wkb, 1024, nullptr, nullptr, pkb8, 512, nullptr, 1024);
    // gi_embed = teb @ Wihb[:, :512]^T -> giEb (bf16), M=6400 N=1536 K=512
    k_mfma_gemm<<<dim3(50, 12), 256, 0, stream>>>(
        nullptr, teb, teb, teb, 512, 512, 512, 512, 512,
        Wihb, 1536, nullptr, giEb, nullptr, 1536, nullptr, 512);

    // ---- scan: 2 wide dispatches per step ----
    for (int t = 0; t < Tdim; t++) {
        float* hcur  = hbuf + (size_t)(t & 1) * 32768;
        float* hnext = hbuf + (size_t)((t + 1) & 1) * 32768;
        k_attn<<<512, 512, 0, stream>>>(pkb8, ehb8, qbuf, We, ctxf, sumcA, t);
        k_mm<<<144, 512, 0, stream>>>(ctxf, sumcA, hb16, Wihb, Whhb, pgi, pgh, csb,
                                      giEb, bih, bhh, hcur, hnext,
                                      Wq8p, qbuf, out_ds, dsb, hb16, out_hl, ctr, t);
    }

    // ---- final: pre = [teb | dsb | csb] @ Wpb^T + bp, M=6400 N=512 K=2048 ----
    k_mfma_gemm<<<dim3(50, 4), 256, 0, stream>>>(
        nullptr, teb, dsb, csb, 512, 512, 1024, 512, 1024,
        Wpb, 2048, out_pre, nullptr, nullptr, 512, bp, 2048);
}

// Round 13
// 5712.375 us; speedup vs baseline: 1.8114x; 1.8114x over previous
//
#include <hip/hip_runtime.h>
#include <cstddef>

// Decoder: B=64, S=400, T=100, E=512, H=512
// R13 = R10 verbatim (best, 4628us; 3 wide dispatches/step, atomic-ctx,
// fp8 Wq GEMV) with ONE change: k_attn phase C uses 8B fp8 loads (uint2,
// 2 row-groups x 128 thr x 8 dims + LDS combine) — pattern proven in R11.
// R11 (fuse: +redundancy) and R12 (ticket-spin: cross-XCD coherence tax)
// both regressed; 3-dispatch structure is the local optimum.

#define Bdim 64
#define Sdim 400
#define Tdim 100
#define Edim 512
#define Hdim 512
#define H2   1024
#define H3   1536

typedef __attribute__((ext_vector_type(8))) short          bf16x8;
typedef __attribute__((ext_vector_type(8))) unsigned short u16x8;
typedef __attribute__((ext_vector_type(4))) float          f32x4;

__device__ __forceinline__ float bf2f(unsigned short u) {
    return __uint_as_float(((unsigned int)u) << 16);
}
__device__ __forceinline__ unsigned short f2bf(float f) {
    unsigned int x = __float_as_uint(f);
    x += 0x7fffu + ((x >> 16) & 1u);
    return (unsigned short)(x >> 16);
}
__device__ __forceinline__ float fast_tanh(float x) {
    float e = __expf(2.0f * x);
    return 1.0f - 2.0f / (e + 1.0f);
}
__device__ __forceinline__ float sigm(float x) {
    return 1.0f / (1.0f + __expf(-x));
}

// ---- OCP e4m3fn encode ----
__device__ __forceinline__ unsigned char f2fp8(float f) {
    unsigned u = __float_as_uint(f);
    unsigned s = (u >> 24) & 0x80u;
    float a = fabsf(f);
    if (a >= 448.0f) return (unsigned char)(s | 0x7Eu);
    if (a < 0.0009765625f) return (unsigned char)s;
    int e = (int)((u >> 23) & 0xFF) - 127;
    if (e < -6) {
        int q = (int)lrintf(a * 512.0f);
        return (unsigned char)(s | (unsigned)q);
    }
    unsigned mant = u & 0x7FFFFFu;
    unsigned keep = mant >> 20;
    unsigned rem  = mant & 0xFFFFFu;
    if (rem > 0x80000u || (rem == 0x80000u && (keep & 1u))) keep++;
    if (keep == 8u) { keep = 0u; e++; if (e > 8) return (unsigned char)(s | 0x7Eu); }
    return (unsigned char)(s | ((unsigned)(e + 7) << 3) | keep);
}

#if defined(__has_builtin)
#if __has_builtin(__builtin_amdgcn_cvt_pk_f32_fp8)
#define HWFP8 1
#endif
#endif
__device__ __forceinline__ float fp8sw(unsigned char v) {
    unsigned e = (v >> 3) & 15u, m = v & 7u, s = v >> 7;
    float f = e ? __uint_as_float(((e + 120u) << 23) | (m << 20))
                : (float)m * 0.001953125f;
    return s ? -f : f;
}
__device__ __forceinline__ void dec4(unsigned int w, float* o) {
#ifdef HWFP8
    auto lo = __builtin_amdgcn_cvt_pk_f32_fp8(w, false);
    auto hi = __builtin_amdgcn_cvt_pk_f32_fp8(w, true);
    o[0] = lo[0]; o[1] = lo[1]; o[2] = hi[0]; o[3] = hi[1];
#else
    o[0] = fp8sw(w & 0xFF); o[1] = fp8sw((w >> 8) & 0xFF);
    o[2] = fp8sw((w >> 16) & 0xFF); o[3] = fp8sw(w >> 24);
#endif
}

// ---------------- one-time kernels ----------------

__global__ void k_cvt(const float4* __restrict__ in, ushort4* __restrict__ out, int n4) {
    int i = blockIdx.x * blockDim.x + threadIdx.x;
    int stride = gridDim.x * blockDim.x;
    for (; i < n4; i += stride) {
        float4 v = in[i];
        ushort4 u;
        u.x = f2bf(v.x); u.y = f2bf(v.y); u.z = f2bf(v.z); u.w = f2bf(v.w);
        out[i] = u;
    }
}

__global__ void k_cvt8(const float4* __restrict__ in, uchar4* __restrict__ out, int n4) {
    int i = blockIdx.x * blockDim.x + threadIdx.x;
    int stride = gridDim.x * blockDim.x;
    for (; i < n4; i += stride) {
        float4 v = in[i];
        uchar4 u;
        u.x = f2fp8(v.x); u.y = f2fp8(v.y); u.z = f2fp8(v.z); u.w = f2fp8(v.w);
        out[i] = u;
    }
}

__global__ void k_cvtW(
    const float4* __restrict__ Wk, const float4* __restrict__ Wih,
    const float4* __restrict__ Whh, const float4* __restrict__ Wp,
    ushort4* __restrict__ oWk, ushort4* __restrict__ oWih,
    ushort4* __restrict__ oWhh, ushort4* __restrict__ oWp)
{
    int i = blockIdx.x * blockDim.x + threadIdx.x;
    int stride = gridDim.x * blockDim.x;
    for (; i < 1179648; i += stride) {
        const float4* src; ushort4* dst; int k = i;
        if (k < 131072)                     { src = Wk;  dst = oWk;  }
        else if ((k -= 131072) < 589824)    { src = Wih; dst = oWih; }
        else if ((k -= 589824) < 196608)    { src = Whh; dst = oWhh; }
        else { k -= 196608;                   src = Wp;  dst = oWp;  }
        float4 v = src[k];
        ushort4 u;
        u.x = f2bf(v.x); u.y = f2bf(v.y); u.z = f2bf(v.z); u.w = f2bf(v.w);
        dst[k] = u;
    }
}

// pack Wq into k4-major fp8: Wq8p[(k4*512 + j)] = fp8x4(Wq[j][4*k4..])
__global__ __launch_bounds__(256) void k_packWq(
    const float* __restrict__ Wq, uchar4* __restrict__ Wq8p)
{
    int i = blockIdx.x * 256 + threadIdx.x;     // 65536 uchar4 elements
    if (i >= 65536) return;
    int k4 = i >> 9, j = i & 511;
    const float* src = Wq + (size_t)j * 512 + (k4 << 2);
    uchar4 u;
    u.x = f2fp8(src[0]); u.y = f2fp8(src[1]);
    u.z = f2fp8(src[2]); u.w = f2fp8(src[3]);
    Wq8p[i] = u;
}

__global__ void k_zero(float* __restrict__ p, int n) {
    int i = blockIdx.x * blockDim.x + threadIdx.x;
    if (i < n) p[i] = 0.0f;
}

__global__ __launch_bounds__(256) void k_init(
    const float* __restrict__ ef, const float* __restrict__ Wi,
    const float* __restrict__ bi, float* __restrict__ h0,
    unsigned short* __restrict__ hb16)
{
    __shared__ float efs[1024];
    int b = blockIdx.x, tid = threadIdx.x;
    for (int i = tid; i < 1024; i += 256) efs[i] = ef[(size_t)b * 1024 + i];
    __syncthreads();
    for (int j = tid; j < 512; j += 256) {
        const float4* w4 = (const float4*)(Wi + (size_t)j * 1024);
        float acc = 0.0f;
        for (int k4 = 0; k4 < 256; k4++) {
            float4 wv = w4[k4];
            int k = k4 << 2;
            acc = fmaf(efs[k],   wv.x, acc);
            acc = fmaf(efs[k+1], wv.y, acc);
            acc = fmaf(efs[k+2], wv.z, acc);
            acc = fmaf(efs[k+3], wv.w, acc);
        }
        float h = fast_tanh(acc + bi[j]);
        h0[(size_t)b * 512 + j] = h;
        hb16[(size_t)b * 512 + j] = f2bf(h);
    }
}

__global__ __launch_bounds__(512) void k_q0(
    const float* __restrict__ h, const float* __restrict__ Wq,
    float* __restrict__ qbuf)
{
    __shared__ float hs[512];
    int b = blockIdx.x, j = threadIdx.x;
    hs[j] = h[(size_t)b * 512 + j];
    __syncthreads();
    const float4* w4 = (const float4*)(Wq + (size_t)j * 512);
    float acc = 0.0f;
    #pragma unroll 4
    for (int k4 = 0; k4 < 128; k4++) {
        float4 wv = w4[k4];
        int k = k4 << 2;
        acc = fmaf(hs[k],   wv.x, acc);
        acc = fmaf(hs[k+1], wv.y, acc);
        acc = fmaf(hs[k+2], wv.z, acc);
        acc = fmaf(hs[k+3], wv.w, acc);
    }
    qbuf[(size_t)b * 512 + j] = acc;
}

// MFMA bf16 GEMM: C[M][N] = A[M][K] @ B[N][K]^T. (verified R2/R4/R7-R12)
__global__ __launch_bounds__(256) void k_mfma_gemm(
    const float* __restrict__ Af,
    const unsigned short* __restrict__ A0, const unsigned short* __restrict__ A1,
    const unsigned short* __restrict__ A2,
    int ld0, int ld1, int ld2, int s1, int s2,
    const unsigned short* __restrict__ Bw, int ldb,
    float* __restrict__ Cf, unsigned short* __restrict__ Cb,
    unsigned char* __restrict__ C8, int ldc,
    const float* __restrict__ bias, int K)
{
    __shared__ __attribute__((aligned(16))) unsigned short As[128][40];
    __shared__ __attribute__((aligned(16))) unsigned short Bs[128][40];
    int m0 = blockIdx.x << 7, n0 = blockIdx.y << 7;
    int tid = threadIdx.x;
    int wave = tid >> 6, lane = tid & 63;
    int wr = (wave >> 1) << 6, wc = (wave & 1) << 6;
    int fr = lane & 15, fq = lane >> 4;
    f32x4 acc[4][4];
    #pragma unroll
    for (int i = 0; i < 4; i++)
        #pragma unroll
        for (int j = 0; j < 4; j++)
            acc[i][j] = (f32x4){0.f, 0.f, 0.f, 0.f};
    int lrow = tid >> 1;
    int lk = (tid & 1) << 4;
    for (int k0 = 0; k0 < K; k0 += 32) {
        u16x8 av0, av1;
        if (Af) {
            const float* ap = Af + (size_t)(m0 + lrow) * ld0 + k0 + lk;
            float4 f0 = *(const float4*)ap;
            float4 f1 = *(const float4*)(ap + 4);
            float4 f2 = *(const float4*)(ap + 8);
            float4 f3 = *(const float4*)(ap + 12);
            av0[0]=f2bf(f0.x); av0[1]=f2bf(f0.y); av0[2]=f2bf(f0.z); av0[3]=f2bf(f0.w);
            av0[4]=f2bf(f1.x); av0[5]=f2bf(f1.y); av0[6]=f2bf(f1.z); av0[7]=f2bf(f1.w);
            av1[0]=f2bf(f2.x); av1[1]=f2bf(f2.y); av1[2]=f2bf(f2.z); av1[3]=f2bf(f2.w);
            av1[4]=f2bf(f3.x); av1[5]=f2bf(f3.y); av1[6]=f2bf(f3.z); av1[7]=f2bf(f3.w);
        } else {
            const unsigned short* Ap; int lda_, ka;
            if (k0 < s1)      { Ap = A0; lda_ = ld0; ka = k0; }
            else if (k0 < s2) { Ap = A1; lda_ = ld1; ka = k0 - s1; }
            else              { Ap = A2; lda_ = ld2; ka = k0 - s2; }
            const unsigned short* ap = Ap + (size_t)(m0 + lrow) * lda_ + ka + lk;
            av0 = *(const u16x8*)ap;
            av1 = *(const u16x8*)(ap + 8);
        }
        const unsigned short* bp_ = Bw + (size_t)(n0 + lrow) * ldb + k0 + lk;
        u16x8 bv0 = *(const u16x8*)bp_;
        u16x8 bv1 = *(const u16x8*)(bp_ + 8);
        __syncthreads();
        *(u16x8*)&As[lrow][lk] = av0;
        *(u16x8*)&As[lrow][lk + 8] = av1;
        *(u16x8*)&Bs[lrow][lk] = bv0;
        *(u16x8*)&Bs[lrow][lk + 8] = bv1;
        __syncthreads();
        bf16x8 af[4], bf[4];
        #pragma unroll
        for (int i = 0; i < 4; i++) {
            af[i] = *(const bf16x8*)&As[wr + (i << 4) + fr][fq << 3];
            bf[i] = *(const bf16x8*)&Bs[wc + (i << 4) + fr][fq << 3];
        }
        #pragma unroll
        for (int i = 0; i < 4; i++)
            #pragma unroll
            for (int j = 0; j < 4; j++)
                acc[i][j] = __builtin_amdgcn_mfma_f32_16x16x32_bf16(af[i], bf[j], acc[i][j], 0, 0, 0);
    }
    #pragma unroll
    for (int j = 0; j < 4; j++) {
        int col = n0 + wc + (j << 4) + fr;
        float bv = bias ? bias[col] : 0.0f;
        #pragma unroll
        for (int i = 0; i < 4; i++) {
            int rbase = m0 + wr + (i << 4) + (fq << 2);
            #pragma unroll
            for (int r = 0; r < 4; r++) {
                float v = acc[i][j][r] + bv;
                if (C8)      C8[(size_t)(rbase + r) * ldc + col] = f2fp8(v);
                else if (Cb) Cb[(size_t)(rbase + r) * ldc + col] = f2bf(v);
                else         Cf[(size_t)(rbase + r) * ldc + col] = v;
            }
        }
    }
}

// ---------------- per-step kernel 1: attention ----------------
// 512 blocks (b = bid>>3, c = bid&7; 8 s-chunks of 50), 256 threads.
// No-max softmax (R4/R10-proven). exp-weighted context accumulated ATOMICALLY
// into complete ctxf[t&1]; sum of exp into sumcA[t&1]. Slot (t&1)^1 zeroed
// here for step t+1 (kernel-boundary ordering makes this safe).
// Phase C: 8B fp8 loads (uint2), 2 row-groups x 128 thr x 8 dims (R11-proven).
__global__ __launch_bounds__(256) void k_attn(
    const unsigned char* __restrict__ pkb8, const unsigned char* __restrict__ ehb8,
    const float* __restrict__ qbuf, const float* __restrict__ We,
    float* __restrict__ ctxf, float* __restrict__ sumcA, int t)
{
    int bid = blockIdx.x;
    int b = bid >> 3, c = bid & 7;
    int s0 = c * 50;
    int tid = threadIdx.x, wave = tid >> 6, lane = tid & 63;
    int s = t & 1;
    __shared__ float eL[52], pL[52];
    __shared__ float cbuf[1024];

    // zero the other ping-pong slot for next step
    {
        int gid = bid * 256 + tid;
        float* octx = ctxf + ((size_t)(1 - s) << 16);
        if (gid < 65536) octx[gid] = 0.0f;
        if (gid < 64) sumcA[(1 - s) * 64 + gid] = 0.0f;
    }

    float q8[8], w8[8];
    {
        const float4* qp = (const float4*)(qbuf + (size_t)b * 512 + (lane << 3));
        float4 q0 = qp[0], q1 = qp[1];
        q8[0]=q0.x; q8[1]=q0.y; q8[2]=q0.z; q8[3]=q0.w;
        q8[4]=q1.x; q8[5]=q1.y; q8[6]=q1.z; q8[7]=q1.w;
        const float4* wp = (const float4*)(We + (lane << 3));
        float4 w0 = wp[0], w1 = wp[1];
        w8[0]=w0.x; w8[1]=w0.y; w8[2]=w0.z; w8[3]=w0.w;
        w8[4]=w1.x; w8[5]=w1.y; w8[6]=w1.z; w8[7]=w1.w;
    }
    // phase A: energies, one wave per s row
    for (int sl = wave; sl < 50; sl += 4) {
        const unsigned char* pr = pkb8 + ((size_t)(b * Sdim + s0 + sl) << 9) + (lane << 3);
        uint2 u = *(const uint2*)pr;
        float p[8];
        dec4(u.x, p); dec4(u.y, p + 4);
        float sum = 0.0f;
        #pragma unroll
        for (int jj = 0; jj < 8; jj++)
            sum = fmaf(fast_tanh(q8[jj] + p[jj]), w8[jj], sum);
        #pragma unroll
        for (int off = 32; off > 0; off >>= 1) sum += __shfl_xor(sum, off, 64);
        if (lane == 0) eL[sl] = sum;
    }
    __syncthreads();
    // phase B: p = exp(e) (energies bounded; no max), chunk sum -> atomic
    if (wave == 0) {
        float pv = 0.0f;
        if (lane < 50) { pv = __expf(eL[lane]); pL[lane] = pv; }
        float ssum = pv;
        #pragma unroll
        for (int off = 32; off > 0; off >>= 1) ssum += __shfl_xor(ssum, off, 64);
        if (lane == 0) atomicAdd(&sumcA[s * 64 + b], ssum);
    }
    __syncthreads();
    // phase C: exp-weighted ctx partial, 8B fp8 loads, 2 row-groups
    int g = tid >> 7, d0 = (tid & 127) << 3;
    float a[8] = {};
    const unsigned char* eb = ehb8 + ((size_t)(b * Sdim + s0) << 10) + d0;
    for (int sl = g; sl < 50; sl += 2) {
        float pp = pL[sl];
        uint2 u = *(const uint2*)(eb + ((size_t)sl << 10));
        float v[8];
        dec4(u.x, v); dec4(u.y, v + 4);
        #pragma unroll
        for (int jj = 0; jj < 8; jj++) a[jj] = fmaf(pp, v[jj], a[jj]);
    }
    if (g) {
        #pragma unroll
        for (int jj = 0; jj < 8; jj++) cbuf[d0 + jj] = a[jj];
    }
    __syncthreads();
    if (!g) {
        float* cp = ctxf + ((size_t)s << 16) + ((size_t)b << 10) + d0;
        #pragma unroll
        for (int jj = 0; jj < 8; jj++)
            atomicAdd(cp + jj, a[jj] + cbuf[d0 + jj]);
    }
}

// ---------------- per-step kernel 2: K-split GRU GEMMs (R10 verbatim) ------
__global__ __launch_bounds__(512) void k_mm(
    const float* __restrict__ ctxf, const float* __restrict__ sumcA,
    const unsigned short* __restrict__ hb16,
    const unsigned short* __restrict__ Wihb, const unsigned short* __restrict__ Whhb,
    float* __restrict__ pgi, float* __restrict__ pgh,
    unsigned short* __restrict__ csb, int t)
{
    __shared__ __attribute__((aligned(16))) unsigned short As[64][264];
    __shared__ __attribute__((aligned(16))) unsigned short Ws[64][72];
    int bid = blockIdx.x, tid = threadIdx.x;
    int wave = tid >> 6, lane = tid & 63;
    int s = t & 1;
    bool isGi = bid < 96;
    int kc, nb;
    if (isGi) { kc = bid / 24; nb = bid - kc * 24; }
    else      { int x = bid - 96; kc = x / 24; nb = x - kc * 24; }
    int n0 = nb << 6;

    int r = tid >> 3, c0 = (tid & 7) << 5;
    if (isGi) {
        float inv = 1.0f / sumcA[s * 64 + r];
        const float* pc = ctxf + ((size_t)s << 16) + ((size_t)r << 10) + (kc << 8) + c0;
        #pragma unroll
        for (int k4 = 0; k4 < 8; k4++) {
            float4 v = *(const float4*)(pc + (k4 << 2));
            ushort4 u;
            u.x = f2bf(v.x * inv); u.y = f2bf(v.y * inv);
            u.z = f2bf(v.z * inv); u.w = f2bf(v.w * inv);
            *(ushort4*)&As[r][c0 + (k4 << 2)] = u;
            if (nb == 0)
                *(ushort4*)&csb[(((size_t)(r * Tdim + t)) << 10) + (kc << 8) + c0 + (k4 << 2)] = u;
        }
    } else {
        const unsigned short* ph = hb16 + (size_t)r * 512 + (kc << 8) + c0;
        *(u16x8*)&As[r][c0]      = *(const u16x8*)ph;
        *(u16x8*)&As[r][c0 + 8]  = *(const u16x8*)(ph + 8);
        *(u16x8*)&As[r][c0 + 16] = *(const u16x8*)(ph + 16);
        *(u16x8*)&As[r][c0 + 24] = *(const u16x8*)(ph + 24);
    }
    __syncthreads();

    const unsigned short* Wsrc = isGi ? (Wihb + (size_t)n0 * H3 + 512 + (kc << 8))
                                      : (Whhb + (size_t)n0 * Hdim + (kc << 8));
    int ldw = isGi ? H3 : Hdim;
    int fr = lane & 15, fq = lane >> 4;
    int fi = wave >> 1, fj0 = (wave & 1) << 1;
    f32x4 acc0 = {0.f,0.f,0.f,0.f}, acc1 = {0.f,0.f,0.f,0.f};
    int rw = tid >> 3, cw2 = (tid & 7) << 3;
    for (int ch = 0; ch < 4; ch++) {
        __syncthreads();
        u16x8 wv8 = *(const u16x8*)(Wsrc + (size_t)rw * ldw + (ch << 6) + cw2);
        *(u16x8*)&Ws[rw][cw2] = wv8;
        __syncthreads();
        #pragma unroll
        for (int ss = 0; ss < 2; ss++) {
            bf16x8 af = *(const bf16x8*)&As[(fi << 4) + fr][(ch << 6) + (ss << 5) + (fq << 3)];
            bf16x8 b0 = *(const bf16x8*)&Ws[(fj0 << 4) + fr][(ss << 5) + (fq << 3)];
            bf16x8 b1 = *(const bf16x8*)&Ws[((fj0 + 1) << 4) + fr][(ss << 5) + (fq << 3)];
            acc0 = __builtin_amdgcn_mfma_f32_16x16x32_bf16(af, b0, acc0, 0, 0, 0);
            acc1 = __builtin_amdgcn_mfma_f32_16x16x32_bf16(af, b1, acc1, 0, 0, 0);
        }
    }
    float* outp = (isGi ? pgi : pgh) + (size_t)kc * Bdim * H3;
    int rowb = (fi << 4) + (fq << 2);
    #pragma unroll
    for (int r4 = 0; r4 < 4; r4++) {
        outp[(size_t)(rowb + r4) * H3 + n0 + (fj0 << 4) + fr] = acc0[r4];
        outp[(size_t)(rowb + r4) * H3 + n0 + ((fj0 + 1) << 4) + fr] = acc1[r4];
    }
}

// ---------------- per-step kernel 3: gates + h + q (fp8 Wq; R10 verbatim) --
__global__ __launch_bounds__(512) void k_gates(
    const float* __restrict__ pgi, const float* __restrict__ pgh,
    const unsigned short* __restrict__ giEb,
    const float* __restrict__ bih, const float* __restrict__ bhh,
    const float* __restrict__ hcur, float* __restrict__ hnext,
    const unsigned char* __restrict__ Wq8p, float* __restrict__ qbuf,
    float* __restrict__ ds, unsigned short* __restrict__ dsb,
    unsigned short* __restrict__ hb16, float* __restrict__ hlast, int t)
{
    int b = blockIdx.x, j = threadIdx.x;
    size_t m = (size_t)b * Tdim + t;
    float gir = 0, giz = 0, gin = 0;
    #pragma unroll
    for (int cc = 0; cc < 4; cc++) {
        const float* p = pgi + ((size_t)cc * Bdim + b) * H3;
        gir += p[j]; giz += p[j + 512]; gin += p[j + 1024];
    }
    const unsigned short* ge = giEb + m * H3;
    gir += bf2f(ge[j]); giz += bf2f(ge[j + 512]); gin += bf2f(ge[j + 1024]);
    float ghr = 0, ghz = 0, ghn = 0;
    #pragma unroll
    for (int cc = 0; cc < 2; cc++) {
        const float* p = pgh + ((size_t)cc * Bdim + b) * H3;
        ghr += p[j]; ghz += p[j + 512]; ghn += p[j + 1024];
    }
    gir += bih[j];        ghr += bhh[j];
    giz += bih[j + 512];  ghz += bhh[j + 512];
    gin += bih[j + 1024]; ghn += bhh[j + 1024];
    float rg = sigm(gir + ghr);
    float z  = sigm(giz + ghz);
    float nn = fast_tanh(gin + rg * ghn);
    float hp = hcur[(size_t)b * 512 + j];
    float hn = (1.0f - z) * nn + z * hp;
    ds[m * 512 + j] = hn;
    dsb[m * 512 + j] = f2bf(hn);
    hb16[(size_t)b * 512 + j] = f2bf(hn);
    hnext[(size_t)b * 512 + j] = hn;
    hlast[(size_t)b * 512 + j] = hn;   // final overwrite = h_last
    // q_{t+1} = h_new @ Wq^T  (fp8 packed k4-major, coalesced; R9-proven)
    __shared__ float hs[512];
    hs[j] = hn;
    __syncthreads();
    float acc = 0.0f;
    const unsigned int* wp = (const unsigned int*)Wq8p + j;
    #pragma unroll 4
    for (int k4 = 0; k4 < 128; k4++) {
        float4 hv = *(const float4*)&hs[k4 << 2];
        unsigned int wv = wp[(size_t)k4 << 9];
        float d[4];
        dec4(wv, d);
        acc = fmaf(hv.x, d[0], acc);
        acc = fmaf(hv.y, d[1], acc);
        acc = fmaf(hv.z, d[2], acc);
        acc = fmaf(hv.w, d[3], acc);
    }
    qbuf[(size_t)b * 512 + j] = acc;
}

extern "C" void kernel_launch(void* const* d_in, const int* in_sizes, int n_in,
                              void* d_out, int out_size, void* d_ws, size_t ws_size,
                              hipStream_t stream) {
    const float* te  = (const float*)d_in[0];
    const float* eh  = (const float*)d_in[1];
    const float* ef  = (const float*)d_in[2];
    const float* Wi  = (const float*)d_in[3];
    const float* bi  = (const float*)d_in[4];
    const float* Wk  = (const float*)d_in[5];
    const float* Wq  = (const float*)d_in[6];
    const float* We  = (const float*)d_in[7];
    const float* Wih = (const float*)d_in[8];
    const float* Whh = (const float*)d_in[9];
    const float* bih = (const float*)d_in[10];
    const float* bhh = (const float*)d_in[11];
    const float* Wp  = (const float*)d_in[12];
    const float* bp  = (const float*)d_in[13];

    float* out     = (float*)d_out;
    float* out_ds  = out;
    float* out_hl  = out + (size_t)Bdim * Tdim * Hdim;
    float* out_pre = out_hl + (size_t)Bdim * Hdim;

    // ---- workspace ----
    char* w = (char*)d_ws;
    size_t o = 0;
    unsigned char*  pkb8 = (unsigned char*)(w + o);  o += (size_t)25600 * 512;
    unsigned char*  ehb8 = (unsigned char*)(w + o);  o += (size_t)25600 * 1024;
    unsigned short* teb  = (unsigned short*)(w + o); o += (size_t)6400 * 512 * 2;
    unsigned short* Wkb  = (unsigned short*)(w + o); o += (size_t)512 * 1024 * 2;
    unsigned short* Wihb = (unsigned short*)(w + o); o += (size_t)1536 * 1536 * 2;
    unsigned short* Whhb = (unsigned short*)(w + o); o += (size_t)1536 * 512 * 2;
    unsigned short* Wpb  = (unsigned short*)(w + o); o += (size_t)512 * 2048 * 2;
    unsigned char*  Wq8p = (unsigned char*)(w + o);  o += (size_t)512 * 512;
    unsigned short* dsb  = (unsigned short*)(w + o); o += (size_t)6400 * 512 * 2;
    unsigned short* csb  = (unsigned short*)(w + o); o += (size_t)6400 * 1024 * 2;
    unsigned short* giEb = (unsigned short*)(w + o); o += (size_t)6400 * 1536 * 2;
    unsigned short* hb16 = (unsigned short*)(w + o); o += (size_t)Bdim * 512 * 2;
    float* qbuf  = (float*)(w + o); o += (size_t)Bdim * 512 * 4;
    float* hbuf  = (float*)(w + o); o += (size_t)2 * Bdim * 512 * 4;   // ping-pong
    float* ctxf  = (float*)(w + o); o += (size_t)2 * Bdim * 1024 * 4;  // ping-pong
    float* sumcA = (float*)(w + o); o += 128 * 4;
    float* pgi   = (float*)(w + o); o += (size_t)4 * Bdim * H3 * 4;
    float* pgh   = (float*)(w + o); o += (size_t)2 * Bdim * H3 * 4;

    // ---- one-time prep ----
    k_cvt8<<<2048, 256, 0, stream>>>((const float4*)eh, (uchar4*)ehb8, 6553600);
    k_cvt<<<512, 256, 0, stream>>>((const float4*)te, (ushort4*)teb, 819200);
    k_cvtW<<<1024, 256, 0, stream>>>(
        (const float4*)Wk, (const float4*)Wih, (const float4*)Whh, (const float4*)Wp,
        (ushort4*)Wkb, (ushort4*)Wihb, (ushort4*)Whhb, (ushort4*)Wpb);
    k_packWq<<<256, 256, 0, stream>>>(Wq, (uchar4*)Wq8p);
    k_zero<<<514, 256, 0, stream>>>(ctxf, 2 * 65536 + 128);   // ctxf + sumcA contiguous
    k_init<<<Bdim, 256, 0, stream>>>(ef, Wi, bi, hbuf, hb16);
    k_q0<<<Bdim, 512, 0, stream>>>(hbuf, Wq, qbuf);
    // proj_key = eh(f32) @ Wkb^T -> pkb8 (fp8), M=25600 N=512 K=1024
    k_mfma_gemm<<<dim3(200, 4), 256, 0, stream>>>(
        eh, nullptr, nullptr, nullptr, 1024, 0, 0, 1024, 1024,
        Wkb, 1024, nullptr, nullptr, pkb8, 512, nullptr, 1024);
    // gi_embed = teb @ Wihb[:, :512]^T -> giEb (bf16), M=6400 N=1536 K=512
    k_mfma_gemm<<<dim3(50, 12), 256, 0, stream>>>(
        nullptr, teb, teb, teb, 512, 512, 512, 512, 512,
        Wihb, 1536, nullptr, giEb, nullptr, 1536, nullptr, 512);

    // ---- scan: 3 wide dispatches per step (R10 structure) ----
    for (int t = 0; t < Tdim; t++) {
        float* hcur  = hbuf + (size_t)(t & 1) * 32768;
        float* hnext = hbuf + (size_t)((t + 1) & 1) * 32768;
        k_attn<<<512, 256, 0, stream>>>(pkb8, ehb8, qbuf, We, ctxf, sumcA, t);
        k_mm<<<144, 512, 0, stream>>>(ctxf, sumcA, hb16, Wihb, Whhb, pgi, pgh, csb, t);
        k_gates<<<Bdim, 512, 0, stream>>>(pgi, pgh, giEb, bih, bhh, hcur, hnext,
                                          Wq8p, qbuf, out_ds, dsb, hb16, out_hl, t);
    }

    // ---- final: pre = [teb | dsb | csb] @ Wpb^T + bp, M=6400 N=512 K=2048 ----
    k_mfma_gemm<<<dim3(50, 4), 256, 0, stream>>>(
        nullptr, teb, dsb, csb, 512, 512, 1024, 512, 1024,
        Wpb, 2048, out_pre, nullptr, nullptr, 512, bp, 2048);
}

// Round 14
// 4645.831 us; speedup vs baseline: 2.2272x; 1.2296x over previous
//
#include <hip/hip_runtime.h>
#include <cstddef>

// Decoder: B=64, S=400, T=100, E=512, H=512
// R14 = R10 byte-for-byte (best measured: 4628us). R11 (+1909, fuse
// redundancy), R12 (+5719, cross-XCD spin), R13 (+1084, burst atomics)
// all regressed — R10's 3-wide-dispatch atomic-ctx structure is the
// empirical optimum. Re-running to confirm noise band + get counters.

#define Bdim 64
#define Sdim 400
#define Tdim 100
#define Edim 512
#define Hdim 512
#define H2   1024
#define H3   1536

typedef __attribute__((ext_vector_type(8))) short          bf16x8;
typedef __attribute__((ext_vector_type(8))) unsigned short u16x8;
typedef __attribute__((ext_vector_type(4))) float          f32x4;

__device__ __forceinline__ float bf2f(unsigned short u) {
    return __uint_as_float(((unsigned int)u) << 16);
}
__device__ __forceinline__ unsigned short f2bf(float f) {
    unsigned int x = __float_as_uint(f);
    x += 0x7fffu + ((x >> 16) & 1u);
    return (unsigned short)(x >> 16);
}
__device__ __forceinline__ float fast_tanh(float x) {
    float e = __expf(2.0f * x);
    return 1.0f - 2.0f / (e + 1.0f);
}
__device__ __forceinline__ float sigm(float x) {
    return 1.0f / (1.0f + __expf(-x));
}

// ---- OCP e4m3fn encode ----
__device__ __forceinline__ unsigned char f2fp8(float f) {
    unsigned u = __float_as_uint(f);
    unsigned s = (u >> 24) & 0x80u;
    float a = fabsf(f);
    if (a >= 448.0f) return (unsigned char)(s | 0x7Eu);
    if (a < 0.0009765625f) return (unsigned char)s;
    int e = (int)((u >> 23) & 0xFF) - 127;
    if (e < -6) {
        int q = (int)lrintf(a * 512.0f);
        return (unsigned char)(s | (unsigned)q);
    }
    unsigned mant = u & 0x7FFFFFu;
    unsigned keep = mant >> 20;
    unsigned rem  = mant & 0xFFFFFu;
    if (rem > 0x80000u || (rem == 0x80000u && (keep & 1u))) keep++;
    if (keep == 8u) { keep = 0u; e++; if (e > 8) return (unsigned char)(s | 0x7Eu); }
    return (unsigned char)(s | ((unsigned)(e + 7) << 3) | keep);
}

#if defined(__has_builtin)
#if __has_builtin(__builtin_amdgcn_cvt_pk_f32_fp8)
#define HWFP8 1
#endif
#endif
__device__ __forceinline__ float fp8sw(unsigned char v) {
    unsigned e = (v >> 3) & 15u, m = v & 7u, s = v >> 7;
    float f = e ? __uint_as_float(((e + 120u) << 23) | (m << 20))
                : (float)m * 0.001953125f;
    return s ? -f : f;
}
__device__ __forceinline__ void dec4(unsigned int w, float* o) {
#ifdef HWFP8
    auto lo = __builtin_amdgcn_cvt_pk_f32_fp8(w, false);
    auto hi = __builtin_amdgcn_cvt_pk_f32_fp8(w, true);
    o[0] = lo[0]; o[1] = lo[1]; o[2] = hi[0]; o[3] = hi[1];
#else
    o[0] = fp8sw(w & 0xFF); o[1] = fp8sw((w >> 8) & 0xFF);
    o[2] = fp8sw((w >> 16) & 0xFF); o[3] = fp8sw(w >> 24);
#endif
}

// ---------------- one-time kernels ----------------

__global__ void k_cvt(const float4* __restrict__ in, ushort4* __restrict__ out, int n4) {
    int i = blockIdx.x * blockDim.x + threadIdx.x;
    int stride = gridDim.x * blockDim.x;
    for (; i < n4; i += stride) {
        float4 v = in[i];
        ushort4 u;
        u.x = f2bf(v.x); u.y = f2bf(v.y); u.z = f2bf(v.z); u.w = f2bf(v.w);
        out[i] = u;
    }
}

__global__ void k_cvt8(const float4* __restrict__ in, uchar4* __restrict__ out, int n4) {
    int i = blockIdx.x * blockDim.x + threadIdx.x;
    int stride = gridDim.x * blockDim.x;
    for (; i < n4; i += stride) {
        float4 v = in[i];
        uchar4 u;
        u.x = f2fp8(v.x); u.y = f2fp8(v.y); u.z = f2fp8(v.z); u.w = f2fp8(v.w);
        out[i] = u;
    }
}

__global__ void k_cvtW(
    const float4* __restrict__ Wk, const float4* __restrict__ Wih,
    const float4* __restrict__ Whh, const float4* __restrict__ Wp,
    ushort4* __restrict__ oWk, ushort4* __restrict__ oWih,
    ushort4* __restrict__ oWhh, ushort4* __restrict__ oWp)
{
    int i = blockIdx.x * blockDim.x + threadIdx.x;
    int stride = gridDim.x * blockDim.x;
    for (; i < 1179648; i += stride) {
        const float4* src; ushort4* dst; int k = i;
        if (k < 131072)                     { src = Wk;  dst = oWk;  }
        else if ((k -= 131072) < 589824)    { src = Wih; dst = oWih; }
        else if ((k -= 589824) < 196608)    { src = Whh; dst = oWhh; }
        else { k -= 196608;                   src = Wp;  dst = oWp;  }
        float4 v = src[k];
        ushort4 u;
        u.x = f2bf(v.x); u.y = f2bf(v.y); u.z = f2bf(v.z); u.w = f2bf(v.w);
        dst[k] = u;
    }
}

// pack Wq into k4-major fp8: Wq8p[(k4*512 + j)] = fp8x4(Wq[j][4*k4..])
__global__ __launch_bounds__(256) void k_packWq(
    const float* __restrict__ Wq, uchar4* __restrict__ Wq8p)
{
    int i = blockIdx.x * 256 + threadIdx.x;     // 65536 uchar4 elements
    if (i >= 65536) return;
    int k4 = i >> 9, j = i & 511;
    const float* src = Wq + (size_t)j * 512 + (k4 << 2);
    uchar4 u;
    u.x = f2fp8(src[0]); u.y = f2fp8(src[1]);
    u.z = f2fp8(src[2]); u.w = f2fp8(src[3]);
    Wq8p[i] = u;
}

__global__ void k_zero(float* __restrict__ p, int n) {
    int i = blockIdx.x * blockDim.x + threadIdx.x;
    if (i < n) p[i] = 0.0f;
}

__global__ __launch_bounds__(256) void k_init(
    const float* __restrict__ ef, const float* __restrict__ Wi,
    const float* __restrict__ bi, float* __restrict__ h0,
    unsigned short* __restrict__ hb16)
{
    __shared__ float efs[1024];
    int b = blockIdx.x, tid = threadIdx.x;
    for (int i = tid; i < 1024; i += 256) efs[i] = ef[(size_t)b * 1024 + i];
    __syncthreads();
    for (int j = tid; j < 512; j += 256) {
        const float4* w4 = (const float4*)(Wi + (size_t)j * 1024);
        float acc = 0.0f;
        for (int k4 = 0; k4 < 256; k4++) {
            float4 wv = w4[k4];
            int k = k4 << 2;
            acc = fmaf(efs[k],   wv.x, acc);
            acc = fmaf(efs[k+1], wv.y, acc);
            acc = fmaf(efs[k+2], wv.z, acc);
            acc = fmaf(efs[k+3], wv.w, acc);
        }
        float h = fast_tanh(acc + bi[j]);
        h0[(size_t)b * 512 + j] = h;
        hb16[(size_t)b * 512 + j] = f2bf(h);
    }
}

__global__ __launch_bounds__(512) void k_q0(
    const float* __restrict__ h, const float* __restrict__ Wq,
    float* __restrict__ qbuf)
{
    __shared__ float hs[512];
    int b = blockIdx.x, j = threadIdx.x;
    hs[j] = h[(size_t)b * 512 + j];
    __syncthreads();
    const float4* w4 = (const float4*)(Wq + (size_t)j * 512);
    float acc = 0.0f;
    #pragma unroll 4
    for (int k4 = 0; k4 < 128; k4++) {
        float4 wv = w4[k4];
        int k = k4 << 2;
        acc = fmaf(hs[k],   wv.x, acc);
        acc = fmaf(hs[k+1], wv.y, acc);
        acc = fmaf(hs[k+2], wv.z, acc);
        acc = fmaf(hs[k+3], wv.w, acc);
    }
    qbuf[(size_t)b * 512 + j] = acc;
}

// MFMA bf16 GEMM: C[M][N] = A[M][K] @ B[N][K]^T. (verified R2/R4/R7-R13)
__global__ __launch_bounds__(256) void k_mfma_gemm(
    const float* __restrict__ Af,
    const unsigned short* __restrict__ A0, const unsigned short* __restrict__ A1,
    const unsigned short* __restrict__ A2,
    int ld0, int ld1, int ld2, int s1, int s2,
    const unsigned short* __restrict__ Bw, int ldb,
    float* __restrict__ Cf, unsigned short* __restrict__ Cb,
    unsigned char* __restrict__ C8, int ldc,
    const float* __restrict__ bias, int K)
{
    __shared__ __attribute__((aligned(16))) unsigned short As[128][40];
    __shared__ __attribute__((aligned(16))) unsigned short Bs[128][40];
    int m0 = blockIdx.x << 7, n0 = blockIdx.y << 7;
    int tid = threadIdx.x;
    int wave = tid >> 6, lane = tid & 63;
    int wr = (wave >> 1) << 6, wc = (wave & 1) << 6;
    int fr = lane & 15, fq = lane >> 4;
    f32x4 acc[4][4];
    #pragma unroll
    for (int i = 0; i < 4; i++)
        #pragma unroll
        for (int j = 0; j < 4; j++)
            acc[i][j] = (f32x4){0.f, 0.f, 0.f, 0.f};
    int lrow = tid >> 1;
    int lk = (tid & 1) << 4;
    for (int k0 = 0; k0 < K; k0 += 32) {
        u16x8 av0, av1;
        if (Af) {
            const float* ap = Af + (size_t)(m0 + lrow) * ld0 + k0 + lk;
            float4 f0 = *(const float4*)ap;
            float4 f1 = *(const float4*)(ap + 4);
            float4 f2 = *(const float4*)(ap + 8);
            float4 f3 = *(const float4*)(ap + 12);
            av0[0]=f2bf(f0.x); av0[1]=f2bf(f0.y); av0[2]=f2bf(f0.z); av0[3]=f2bf(f0.w);
            av0[4]=f2bf(f1.x); av0[5]=f2bf(f1.y); av0[6]=f2bf(f1.z); av0[7]=f2bf(f1.w);
            av1[0]=f2bf(f2.x); av1[1]=f2bf(f2.y); av1[2]=f2bf(f2.z); av1[3]=f2bf(f2.w);
            av1[4]=f2bf(f3.x); av1[5]=f2bf(f3.y); av1[6]=f2bf(f3.z); av1[7]=f2bf(f3.w);
        } else {
            const unsigned short* Ap; int lda_, ka;
            if (k0 < s1)      { Ap = A0; lda_ = ld0; ka = k0; }
            else if (k0 < s2) { Ap = A1; lda_ = ld1; ka = k0 - s1; }
            else              { Ap = A2; lda_ = ld2; ka = k0 - s2; }
            const unsigned short* ap = Ap + (size_t)(m0 + lrow) * lda_ + ka + lk;
            av0 = *(const u16x8*)ap;
            av1 = *(const u16x8*)(ap + 8);
        }
        const unsigned short* bp_ = Bw + (size_t)(n0 + lrow) * ldb + k0 + lk;
        u16x8 bv0 = *(const u16x8*)bp_;
        u16x8 bv1 = *(const u16x8*)(bp_ + 8);
        __syncthreads();
        *(u16x8*)&As[lrow][lk] = av0;
        *(u16x8*)&As[lrow][lk + 8] = av1;
        *(u16x8*)&Bs[lrow][lk] = bv0;
        *(u16x8*)&Bs[lrow][lk + 8] = bv1;
        __syncthreads();
        bf16x8 af[4], bf[4];
        #pragma unroll
        for (int i = 0; i < 4; i++) {
            af[i] = *(const bf16x8*)&As[wr + (i << 4) + fr][fq << 3];
            bf[i] = *(const bf16x8*)&Bs[wc + (i << 4) + fr][fq << 3];
        }
        #pragma unroll
        for (int i = 0; i < 4; i++)
            #pragma unroll
            for (int j = 0; j < 4; j++)
                acc[i][j] = __builtin_amdgcn_mfma_f32_16x16x32_bf16(af[i], bf[j], acc[i][j], 0, 0, 0);
    }
    #pragma unroll
    for (int j = 0; j < 4; j++) {
        int col = n0 + wc + (j << 4) + fr;
        float bv = bias ? bias[col] : 0.0f;
        #pragma unroll
        for (int i = 0; i < 4; i++) {
            int rbase = m0 + wr + (i << 4) + (fq << 2);
            #pragma unroll
            for (int r = 0; r < 4; r++) {
                float v = acc[i][j][r] + bv;
                if (C8)      C8[(size_t)(rbase + r) * ldc + col] = f2fp8(v);
                else if (Cb) Cb[(size_t)(rbase + r) * ldc + col] = f2bf(v);
                else         Cf[(size_t)(rbase + r) * ldc + col] = v;
            }
        }
    }
}

// ---------------- per-step kernel 1: attention ----------------
// 512 blocks (b = bid>>3, c = bid&7; 8 s-chunks of 50), 256 threads.
// No-max softmax (R4-proven). exp-weighted context accumulated ATOMICALLY
// into complete ctxf[t&1]; sum of exp into sumcA[t&1]. Slot (t&1)^1 is
// zeroed here for step t+1 (kernel-boundary ordering makes this safe).
__global__ __launch_bounds__(256) void k_attn(
    const unsigned char* __restrict__ pkb8, const unsigned char* __restrict__ ehb8,
    const float* __restrict__ qbuf, const float* __restrict__ We,
    float* __restrict__ ctxf, float* __restrict__ sumcA, int t)
{
    int bid = blockIdx.x;
    int b = bid >> 3, c = bid & 7;
    int s0 = c * 50;
    int tid = threadIdx.x, wave = tid >> 6, lane = tid & 63;
    int s = t & 1;
    __shared__ float eL[52], pL[52];

    // zero the other ping-pong slot for next step
    {
        int gid = bid * 256 + tid;
        float* octx = ctxf + ((size_t)(1 - s) << 16);
        if (gid < 65536) octx[gid] = 0.0f;
        if (gid < 64) sumcA[(1 - s) * 64 + gid] = 0.0f;
    }

    float q8[8], w8[8];
    {
        const float4* qp = (const float4*)(qbuf + (size_t)b * 512 + (lane << 3));
        float4 q0 = qp[0], q1 = qp[1];
        q8[0]=q0.x; q8[1]=q0.y; q8[2]=q0.z; q8[3]=q0.w;
        q8[4]=q1.x; q8[5]=q1.y; q8[6]=q1.z; q8[7]=q1.w;
        const float4* wp = (const float4*)(We + (lane << 3));
        float4 w0 = wp[0], w1 = wp[1];
        w8[0]=w0.x; w8[1]=w0.y; w8[2]=w0.z; w8[3]=w0.w;
        w8[4]=w1.x; w8[5]=w1.y; w8[6]=w1.z; w8[7]=w1.w;
    }
    // phase A: energies, one wave per s row
    for (int sl = wave; sl < 50; sl += 4) {
        const unsigned char* pr = pkb8 + ((size_t)(b * Sdim + s0 + sl) << 9) + (lane << 3);
        uint2 u = *(const uint2*)pr;
        float p[8];
        dec4(u.x, p); dec4(u.y, p + 4);
        float sum = 0.0f;
        #pragma unroll
        for (int jj = 0; jj < 8; jj++)
            sum = fmaf(fast_tanh(q8[jj] + p[jj]), w8[jj], sum);
        #pragma unroll
        for (int off = 32; off > 0; off >>= 1) sum += __shfl_xor(sum, off, 64);
        if (lane == 0) eL[sl] = sum;
    }
    __syncthreads();
    // phase B: p = exp(e) (energies bounded; no max — R4-proven), chunk sum
    if (wave == 0) {
        float pv = 0.0f;
        if (lane < 50) { pv = __expf(eL[lane]); pL[lane] = pv; }
        float ssum = pv;
        #pragma unroll
        for (int off = 32; off > 0; off >>= 1) ssum += __shfl_xor(ssum, off, 64);
        if (lane == 0) atomicAdd(&sumcA[s * 64 + b], ssum);
    }
    __syncthreads();
    // phase C: exp-weighted context, atomically accumulated (complete ctx)
    int d0 = tid << 2;
    float a0 = 0.f, a1 = 0.f, a2 = 0.f, a3 = 0.f;
    const unsigned char* eb = ehb8 + ((size_t)(b * Sdim + s0) << 10) + d0;
    for (int sl = 0; sl < 50; sl++) {
        float pp = pL[sl];
        unsigned int u = *(const unsigned int*)(eb + ((size_t)sl << 10));
        float v[4];
        dec4(u, v);
        a0 = fmaf(pp, v[0], a0);
        a1 = fmaf(pp, v[1], a1);
        a2 = fmaf(pp, v[2], a2);
        a3 = fmaf(pp, v[3], a3);
    }
    float* cp = ctxf + ((size_t)s << 16) + ((size_t)b << 10) + d0;
    atomicAdd(cp + 0, a0);
    atomicAdd(cp + 1, a1);
    atomicAdd(cp + 2, a2);
    atomicAdd(cp + 3, a3);
}

// ---------------- per-step kernel 2: K-split GRU GEMMs ----------
// 144 blocks x 512 thr: 0..95 gi-ctx (4 K-chunks x 24 N), 96..143 gh (2 x 24).
// Reads COMPLETE ctxf (atomic-combined) — no per-block combine.
__global__ __launch_bounds__(512) void k_mm(
    const float* __restrict__ ctxf, const float* __restrict__ sumcA,
    const unsigned short* __restrict__ hb16,
    const unsigned short* __restrict__ Wihb, const unsigned short* __restrict__ Whhb,
    float* __restrict__ pgi, float* __restrict__ pgh,
    unsigned short* __restrict__ csb, int t)
{
    __shared__ __attribute__((aligned(16))) unsigned short As[64][264];
    __shared__ __attribute__((aligned(16))) unsigned short Ws[64][72];
    int bid = blockIdx.x, tid = threadIdx.x;
    int wave = tid >> 6, lane = tid & 63;
    int s = t & 1;
    bool isGi = bid < 96;
    int kc, nb;
    if (isGi) { kc = bid / 24; nb = bid - kc * 24; }
    else      { int x = bid - 96; kc = x / 24; nb = x - kc * 24; }
    int n0 = nb << 6;

    int r = tid >> 3, c0 = (tid & 7) << 5;
    if (isGi) {
        float inv = 1.0f / sumcA[s * 64 + r];
        const float* pc = ctxf + ((size_t)s << 16) + ((size_t)r << 10) + (kc << 8) + c0;
        #pragma unroll
        for (int k4 = 0; k4 < 8; k4++) {
            float4 v = *(const float4*)(pc + (k4 << 2));
            ushort4 u;
            u.x = f2bf(v.x * inv); u.y = f2bf(v.y * inv);
            u.z = f2bf(v.z * inv); u.w = f2bf(v.w * inv);
            *(ushort4*)&As[r][c0 + (k4 << 2)] = u;
            if (nb == 0)
                *(ushort4*)&csb[(((size_t)(r * Tdim + t)) << 10) + (kc << 8) + c0 + (k4 << 2)] = u;
        }
    } else {
        const unsigned short* ph = hb16 + (size_t)r * 512 + (kc << 8) + c0;
        *(u16x8*)&As[r][c0]      = *(const u16x8*)ph;
        *(u16x8*)&As[r][c0 + 8]  = *(const u16x8*)(ph + 8);
        *(u16x8*)&As[r][c0 + 16] = *(const u16x8*)(ph + 16);
        *(u16x8*)&As[r][c0 + 24] = *(const u16x8*)(ph + 24);
    }
    __syncthreads();

    const unsigned short* Wsrc = isGi ? (Wihb + (size_t)n0 * H3 + 512 + (kc << 8))
                                      : (Whhb + (size_t)n0 * Hdim + (kc << 8));
    int ldw = isGi ? H3 : Hdim;
    int fr = lane & 15, fq = lane >> 4;
    int fi = wave >> 1, fj0 = (wave & 1) << 1;
    f32x4 acc0 = {0.f,0.f,0.f,0.f}, acc1 = {0.f,0.f,0.f,0.f};
    int rw = tid >> 3, cw2 = (tid & 7) << 3;
    for (int ch = 0; ch < 4; ch++) {
        __syncthreads();
        u16x8 wv8 = *(const u16x8*)(Wsrc + (size_t)rw * ldw + (ch << 6) + cw2);
        *(u16x8*)&Ws[rw][cw2] = wv8;
        __syncthreads();
        #pragma unroll
        for (int ss = 0; ss < 2; ss++) {
            bf16x8 af = *(const bf16x8*)&As[(fi << 4) + fr][(ch << 6) + (ss << 5) + (fq << 3)];
            bf16x8 b0 = *(const bf16x8*)&Ws[(fj0 << 4) + fr][(ss << 5) + (fq << 3)];
            bf16x8 b1 = *(const bf16x8*)&Ws[((fj0 + 1) << 4) + fr][(ss << 5) + (fq << 3)];
            acc0 = __builtin_amdgcn_mfma_f32_16x16x32_bf16(af, b0, acc0, 0, 0, 0);
            acc1 = __builtin_amdgcn_mfma_f32_16x16x32_bf16(af, b1, acc1, 0, 0, 0);
        }
    }
    float* outp = (isGi ? pgi : pgh) + (size_t)kc * Bdim * H3;
    int rowb = (fi << 4) + (fq << 2);
    #pragma unroll
    for (int r4 = 0; r4 < 4; r4++) {
        outp[(size_t)(rowb + r4) * H3 + n0 + (fj0 << 4) + fr] = acc0[r4];
        outp[(size_t)(rowb + r4) * H3 + n0 + ((fj0 + 1) << 4) + fr] = acc1[r4];
    }
}

// ---------------- per-step kernel 3: gates + h + q (fp8 Wq) ----------------
__global__ __launch_bounds__(512) void k_gates(
    const float* __restrict__ pgi, const float* __restrict__ pgh,
    const unsigned short* __restrict__ giEb,
    const float* __restrict__ bih, const float* __restrict__ bhh,
    const float* __restrict__ hcur, float* __restrict__ hnext,
    const unsigned char* __restrict__ Wq8p, float* __restrict__ qbuf,
    float* __restrict__ ds, unsigned short* __restrict__ dsb,
    unsigned short* __restrict__ hb16, float* __restrict__ hlast, int t)
{
    int b = blockIdx.x, j = threadIdx.x;
    size_t m = (size_t)b * Tdim + t;
    float gir = 0, giz = 0, gin = 0;
    #pragma unroll
    for (int cc = 0; cc < 4; cc++) {
        const float* p = pgi + ((size_t)cc * Bdim + b) * H3;
        gir += p[j]; giz += p[j + 512]; gin += p[j + 1024];
    }
    const unsigned short* ge = giEb + m * H3;
    gir += bf2f(ge[j]); giz += bf2f(ge[j + 512]); gin += bf2f(ge[j + 1024]);
    float ghr = 0, ghz = 0, ghn = 0;
    #pragma unroll
    for (int cc = 0; cc < 2; cc++) {
        const float* p = pgh + ((size_t)cc * Bdim + b) * H3;
        ghr += p[j]; ghz += p[j + 512]; ghn += p[j + 1024];
    }
    gir += bih[j];        ghr += bhh[j];
    giz += bih[j + 512];  ghz += bhh[j + 512];
    gin += bih[j + 1024]; ghn += bhh[j + 1024];
    float rg = sigm(gir + ghr);
    float z  = sigm(giz + ghz);
    float nn = fast_tanh(gin + rg * ghn);
    float hp = hcur[(size_t)b * 512 + j];
    float hn = (1.0f - z) * nn + z * hp;
    ds[m * 512 + j] = hn;
    dsb[m * 512 + j] = f2bf(hn);
    hb16[(size_t)b * 512 + j] = f2bf(hn);
    hnext[(size_t)b * 512 + j] = hn;
    hlast[(size_t)b * 512 + j] = hn;   // final overwrite = h_last
    // q_{t+1} = h_new @ Wq^T  (fp8 packed k4-major, coalesced; R9-proven)
    __shared__ float hs[512];
    hs[j] = hn;
    __syncthreads();
    float acc = 0.0f;
    const unsigned int* wp = (const unsigned int*)Wq8p + j;
    #pragma unroll 4
    for (int k4 = 0; k4 < 128; k4++) {
        float4 hv = *(const float4*)&hs[k4 << 2];
        unsigned int wv = wp[(size_t)k4 << 9];
        float d[4];
        dec4(wv, d);
        acc = fmaf(hv.x, d[0], acc);
        acc = fmaf(hv.y, d[1], acc);
        acc = fmaf(hv.z, d[2], acc);
        acc = fmaf(hv.w, d[3], acc);
    }
    qbuf[(size_t)b * 512 + j] = acc;
}

extern "C" void kernel_launch(void* const* d_in, const int* in_sizes, int n_in,
                              void* d_out, int out_size, void* d_ws, size_t ws_size,
                              hipStream_t stream) {
    const float* te  = (const float*)d_in[0];
    const float* eh  = (const float*)d_in[1];
    const float* ef  = (const float*)d_in[2];
    const float* Wi  = (const float*)d_in[3];
    const float* bi  = (const float*)d_in[4];
    const float* Wk  = (const float*)d_in[5];
    const float* Wq  = (const float*)d_in[6];
    const float* We  = (const float*)d_in[7];
    const float* Wih = (const float*)d_in[8];
    const float* Whh = (const float*)d_in[9];
    const float* bih = (const float*)d_in[10];
    const float* bhh = (const float*)d_in[11];
    const float* Wp  = (const float*)d_in[12];
    const float* bp  = (const float*)d_in[13];

    float* out     = (float*)d_out;
    float* out_ds  = out;
    float* out_hl  = out + (size_t)Bdim * Tdim * Hdim;
    float* out_pre = out_hl + (size_t)Bdim * Hdim;

    // ---- workspace ----
    char* w = (char*)d_ws;
    size_t o = 0;
    unsigned char*  pkb8 = (unsigned char*)(w + o);  o += (size_t)25600 * 512;
    unsigned char*  ehb8 = (unsigned char*)(w + o);  o += (size_t)25600 * 1024;
    unsigned short* teb  = (unsigned short*)(w + o); o += (size_t)6400 * 512 * 2;
    unsigned short* Wkb  = (unsigned short*)(w + o); o += (size_t)512 * 1024 * 2;
    unsigned short* Wihb = (unsigned short*)(w + o); o += (size_t)1536 * 1536 * 2;
    unsigned short* Whhb = (unsigned short*)(w + o); o += (size_t)1536 * 512 * 2;
    unsigned short* Wpb  = (unsigned short*)(w + o); o += (size_t)512 * 2048 * 2;
    unsigned char*  Wq8p = (unsigned char*)(w + o);  o += (size_t)512 * 512;
    unsigned short* dsb  = (unsigned short*)(w + o); o += (size_t)6400 * 512 * 2;
    unsigned short* csb  = (unsigned short*)(w + o); o += (size_t)6400 * 1024 * 2;
    unsigned short* giEb = (unsigned short*)(w + o); o += (size_t)6400 * 1536 * 2;
    unsigned short* hb16 = (unsigned short*)(w + o); o += (size_t)Bdim * 512 * 2;
    float* qbuf  = (float*)(w + o); o += (size_t)Bdim * 512 * 4;
    float* hbuf  = (float*)(w + o); o += (size_t)2 * Bdim * 512 * 4;   // ping-pong
    float* ctxf  = (float*)(w + o); o += (size_t)2 * Bdim * 1024 * 4;  // ping-pong
    float* sumcA = (float*)(w + o); o += 128 * 4;
    float* pgi   = (float*)(w + o); o += (size_t)4 * Bdim * H3 * 4;
    float* pgh   = (float*)(w + o); o += (size_t)2 * Bdim * H3 * 4;

    // ---- one-time prep ----
    k_cvt8<<<2048, 256, 0, stream>>>((const float4*)eh, (uchar4*)ehb8, 6553600);
    k_cvt<<<512, 256, 0, stream>>>((const float4*)te, (ushort4*)teb, 819200);
    k_cvtW<<<1024, 256, 0, stream>>>(
        (const float4*)Wk, (const float4*)Wih, (const float4*)Whh, (const float4*)Wp,
        (ushort4*)Wkb, (ushort4*)Wihb, (ushort4*)Whhb, (ushort4*)Wpb);
    k_packWq<<<256, 256, 0, stream>>>(Wq, (uchar4*)Wq8p);
    k_zero<<<514, 256, 0, stream>>>(ctxf, 2 * 65536 + 128);   // ctxf + sumcA contiguous
    k_init<<<Bdim, 256, 0, stream>>>(ef, Wi, bi, hbuf, hb16);
    k_q0<<<Bdim, 512, 0, stream>>>(hbuf, Wq, qbuf);
    // proj_key = eh(f32) @ Wkb^T -> pkb8 (fp8), M=25600 N=512 K=1024
    k_mfma_gemm<<<dim3(200, 4), 256, 0, stream>>>(
        eh, nullptr, nullptr, nullptr, 1024, 0, 0, 1024, 1024,
        Wkb, 1024, nullptr, nullptr, pkb8, 512, nullptr, 1024);
    // gi_embed = teb @ Wihb[:, :512]^T -> giEb (bf16), M=6400 N=1536 K=512
    k_mfma_gemm<<<dim3(50, 12), 256, 0, stream>>>(
        nullptr, teb, teb, teb, 512, 512, 512, 512, 512,
        Wihb, 1536, nullptr, giEb, nullptr, 1536, nullptr, 512);

    // ---- scan: 3 wide dispatches per step (R10 structure) ----
    for (int t = 0; t < Tdim; t++) {
        float* hcur  = hbuf + (size_t)(t & 1) * 32768;
        float* hnext = hbuf + (size_t)((t + 1) & 1) * 32768;
        k_attn<<<512, 256, 0, stream>>>(pkb8, ehb8, qbuf, We, ctxf, sumcA, t);
        k_mm<<<144, 512, 0, stream>>>(ctxf, sumcA, hb16, Wihb, Whhb, pgi, pgh, csb, t);
        k_gates<<<Bdim, 512, 0, stream>>>(pgi, pgh, giEb, bih, bhh, hcur, hnext,
                                          Wq8p, qbuf, out_ds, dsb, hb16, out_hl, t);
    }

    // ---- final: pre = [teb | dsb | csb] @ Wpb^T + bp, M=6400 N=512 K=2048 ----
    k_mfma_gemm<<<dim3(50, 4), 256, 0, stream>>>(
        nullptr, teb, dsb, csb, 512, 512, 1024, 512, 1024,
        Wpb, 2048, out_pre, nullptr, nullptr, 512, bp, 2048);
}